// Round 4
// baseline (689.164 us; speedup 1.0000x reference)
//
#include <hip/hip_runtime.h>
#include <hip/hip_cooperative_groups.h>
#include <stdint.h>

// GriddingDistance fwd, R9. R8 post-mortem: 386 us = ~222 harness poison tax
// + ~164 us over 5 serial dispatches whose memory floor is only ~55 us. The
// structural waste: qrec's 32 MB round-trip exists ONLY to ferry pass-A
// registers to pass C, plus 4 inter-pass launch gaps and 2 latency-bound scan
// launches. R9 fuses A+scan+C into ONE cooperative kernel (512x512 = exactly
// 2 blocks/CU co-resident, 2 KB LDS, VGPR<=128): records live in lrec[2][4]
// registers across hist -> column-scan -> base-scan -> scatter, separated by
// grid.sync(). Pass D (8192x256, proven shape) stays separate. Cooperative
// launch return code checked -> fall back to the R8 5-kernel path on failure.

namespace cg = cooperative_groups;

constexpr int R    = 128;
constexpr int R3c  = R * R * R;
constexpr int BPG  = 256;            // bins per (cloud,batch): 8 x 8 x 4 regions of 16x16x32
constexpr int NBLK = 512;            // sort blocks
constexpr int BLKT = 512;            // threads per sort block
constexpr int MAXB = 128;            // max batch count supported by ws layout

// ws layout (byte offsets); harness ws = 1 GiB
constexpr size_t WS_HIST = 0;                 // NBLK*BPG*4 = 512 KB
constexpr size_t WS_TOT  = 768u << 10;        // NBINS*4 (<= 256 KB)
constexpr size_t WS_BASE = 1u << 20;          // (NBINS+1)*4
constexpr size_t WS_QREC = 2u << 20;          // P*8 = 16 MB (fallback path only)
constexpr size_t WS_REC  = 20u << 20;         // worst case 8P*8 = 128 MB

typedef float f4v __attribute__((ext_vector_type(4)));

// ---- quantization: v = (p/128 + 0.5)*128 == p + 64 (<=1 ulp), vq = rn(v*2^14),
// clamped so ix = vq>>14 <= 126. All binning/weights derive from vq.
__device__ __forceinline__ uint32_t quant1(float p) {
    const float S = 16384.0f;                  // 2^14
    const uint32_t QMAX = (126u << 14) | 16383u;
    float v = p + 64.0f;
    return min(__float2uint_rn(fmaxf(v, 0.0f) * S), QMAX);
}

__device__ __forceinline__ uint2 pack_rec(uint32_t xq, uint32_t yq, uint32_t zq) {
    return make_uint2(xq | (yq << 21), (yq >> 11) | (zq << 10));
}
__device__ __forceinline__ void unpack_rec(uint2 r, uint32_t& xq, uint32_t& yq, uint32_t& zq) {
    xq = r.x & 0x1FFFFFu;
    yq = (r.x >> 21) | ((r.y & 0x3FFu) << 11);
    zq = (r.y >> 10) & 0x1FFFFFu;
}

// local (within cloud,batch) region bounds from quantized cell coords
__device__ __forceinline__ void region_range(uint32_t xq, uint32_t yq, uint32_t zq,
                                             int& rx0, int& rx1, int& ry0, int& ry1,
                                             int& rz0, int& rz1)
{
    int ix = xq >> 14, iy = yq >> 14, iz = zq >> 14;
    rx0 = ix >> 4; rx1 = (ix + 1) >> 4;
    ry0 = iy >> 4; ry1 = (iy + 1) >> 4;
    rz0 = iz >> 5; rz1 = (iz + 1) >> 5;
}

// =================== fused cooperative sort (hist+scan+scatter) ===================
// preconditions (host-checked): P == NBLK*ppb, ppb == 8*BLKT (2 groups of 4
// points per thread), every block inside ONE (cloud,batch), NBINS % BLKT == 0,
// NBINS <= NBLK*BLKT.
__global__ __launch_bounds__(BLKT, 4) void fused_sort(
    const float* __restrict__ pred, const float* __restrict__ gt,
    int total1, int P, int ppb, int B, int nb1, int bpg1, int bpg2, int NBINS,
    uint32_t* __restrict__ hist, uint32_t* __restrict__ tot,
    uint32_t* __restrict__ base, uint2* __restrict__ records)
{
    __shared__ uint32_t shm[BLKT];                 // 2 KB (hist / partials / cursors)
    cg::grid_group grid = cg::this_grid();

    // ---- phase 1: per-block 256-bin histogram; records stay in registers ----
    if (threadIdx.x < BPG) shm[threadIdx.x] = 0;
    __syncthreads();

    int s = blockIdx.x * ppb;
    bool isgt = (s >= total1);
    const float4* src4 = (const float4*)(isgt ? gt + (size_t)(s - total1) * 3
                                              : pred + (size_t)s * 3);
    uint2 lrec[2][4];
    #pragma unroll
    for (int it = 0; it < 2; ++it) {
        int g = threadIdx.x + it * BLKT;
        float4 a  = src4[g * 3 + 0];
        float4 b4 = src4[g * 3 + 1];
        float4 c4 = src4[g * 3 + 2];
        float xs[4] = {a.x, a.w, b4.z, c4.y};
        float ys[4] = {a.y, b4.x, b4.w, c4.z};
        float zs[4] = {a.z, b4.y, c4.x, c4.w};
        #pragma unroll
        for (int q = 0; q < 4; ++q) {
            uint32_t xq = quant1(xs[q]), yq = quant1(ys[q]), zq = quant1(zs[q]);
            lrec[it][q] = pack_rec(xq, yq, zq);
            int rx0, rx1, ry0, ry1, rz0, rz1;
            region_range(xq, yq, zq, rx0, rx1, ry0, ry1, rz0, rz1);
            for (int aa = rx0; aa <= rx1; ++aa)
                for (int bb = ry0; bb <= ry1; ++bb)
                    for (int cc = rz0; cc <= rz1; ++cc)
                        atomicAdd(&shm[(aa << 5) + (bb << 2) + cc], 1u);
        }
    }
    __syncthreads();
    if (threadIdx.x < BPG)
        hist[(size_t)blockIdx.x * BPG + threadIdx.x] = shm[threadIdx.x];
    __threadfence();
    grid.sync();

    // ---- phase 2a: per-bin column scan over that bin's contributing blocks ----
    int tid = blockIdx.x * BLKT + threadIdx.x;
    if (tid < NBINS) {
        int cb = tid >> 8, l = tid & 255;
        int first = (cb < B) ? cb * bpg1 : nb1 + (cb - B) * bpg2;
        int cnt   = (cb < B) ? bpg1 : bpg2;
        uint32_t run = 0;
        for (int k = 0; k < cnt; ++k) {
            size_t idx = (size_t)(first + k) * BPG + l;
            uint32_t t = hist[idx];
            hist[idx] = run;
            run += t;
        }
        tot[tid] = run;
    }
    __threadfence();
    grid.sync();

    // ---- phase 2b: exclusive scan of bin totals (block 0) ----
    if (blockIdx.x == 0) {
        int t = threadIdx.x;
        int chunk = NBINS / BLKT;                  // 16
        uint32_t ssum = 0;
        for (int i = 0; i < chunk; ++i) ssum += tot[t * chunk + i];
        shm[t] = ssum;
        __syncthreads();
        if (t == 0) {
            uint32_t run = 0;
            for (int i = 0; i < BLKT; ++i) { uint32_t v = shm[i]; shm[i] = run; run += v; }
        }
        __syncthreads();
        uint32_t run = shm[t];
        for (int i = 0; i < chunk; ++i) {
            base[t * chunk + i] = run;
            run += tot[t * chunk + i];
        }
        if (t == BLKT - 1) base[NBINS] = run;
    }
    __threadfence();
    grid.sync();

    // ---- phase 3: deterministic scatter of the in-register records ----
    int cbb = (blockIdx.x < nb1) ? (blockIdx.x / bpg1)
                                 : (B + (blockIdx.x - nb1) / bpg2);
    if (threadIdx.x < BPG)
        shm[threadIdx.x] = base[cbb * BPG + threadIdx.x] +
                           hist[(size_t)blockIdx.x * BPG + threadIdx.x];
    __syncthreads();

    #pragma unroll
    for (int it = 0; it < 2; ++it) {
        #pragma unroll
        for (int q = 0; q < 4; ++q) {
            uint2 rec = lrec[it][q];
            uint32_t xq, yq, zq;
            unpack_rec(rec, xq, yq, zq);
            int rx0, rx1, ry0, ry1, rz0, rz1;
            region_range(xq, yq, zq, rx0, rx1, ry0, ry1, rz0, rz1);
            for (int aa = rx0; aa <= rx1; ++aa)
                for (int bb = ry0; bb <= ry1; ++bb)
                    for (int cc = rz0; cc <= rz1; ++cc) {
                        uint32_t slot = atomicAdd(&shm[(aa << 5) + (bb << 2) + cc], 1u);
                        records[slot] = rec;
                    }
        }
    }
}

// =================== R8 fallback pipeline (non-cooperative) ===================

__global__ __launch_bounds__(BLKT) void bin_hist_qrec(
    const float* __restrict__ pred, const float* __restrict__ gt,
    int total1, int P, int ppb,
    uint32_t* __restrict__ hist, uint2* __restrict__ qrec)
{
    __shared__ uint32_t h[BPG];
    if (threadIdx.x < BPG) h[threadIdx.x] = 0;
    __syncthreads();

    int s = blockIdx.x * ppb;
    if (s < P) {
        int e = min(s + ppb, P);
        bool isgt = (s >= total1);
        const float* src = isgt ? gt + (size_t)(s - total1) * 3
                                : pred + (size_t)s * 3;
        const float4* src4 = (const float4*)src;
        int ngrp = (e - s) >> 2;
        for (int g = threadIdx.x; g < ngrp; g += BLKT) {
            float4 a  = src4[g * 3 + 0];
            float4 b4 = src4[g * 3 + 1];
            float4 c4 = src4[g * 3 + 2];
            float xs[4] = {a.x, a.w, b4.z, c4.y};
            float ys[4] = {a.y, b4.x, b4.w, c4.z};
            float zs[4] = {a.z, b4.y, c4.x, c4.w};
            uint2 rec[4];
            #pragma unroll
            for (int q = 0; q < 4; ++q) {
                uint32_t xq = quant1(xs[q]), yq = quant1(ys[q]), zq = quant1(zs[q]);
                rec[q] = pack_rec(xq, yq, zq);
                int rx0, rx1, ry0, ry1, rz0, rz1;
                region_range(xq, yq, zq, rx0, rx1, ry0, ry1, rz0, rz1);
                for (int aa = rx0; aa <= rx1; ++aa)
                    for (int bb = ry0; bb <= ry1; ++bb)
                        for (int cc = rz0; cc <= rz1; ++cc)
                            atomicAdd(&h[(aa << 5) + (bb << 2) + cc], 1u);
            }
            uint4* q4 = (uint4*)(qrec + (size_t)s + (size_t)g * 4);
            q4[0] = make_uint4(rec[0].x, rec[0].y, rec[1].x, rec[1].y);
            q4[1] = make_uint4(rec[2].x, rec[2].y, rec[3].x, rec[3].y);
        }
    }
    __syncthreads();
    if (threadIdx.x < BPG)
        hist[(size_t)blockIdx.x * BPG + threadIdx.x] = h[threadIdx.x];
}

__global__ __launch_bounds__(256) void scan1(
    uint32_t* __restrict__ hist, uint32_t* __restrict__ tot,
    int B, int nb1, int bpg1, int bpg2, int NBINS)
{
    int j = blockIdx.x * 256 + threadIdx.x;
    if (j >= NBINS) return;
    int cb = j >> 8, l = j & 255;
    int first = (cb < B) ? cb * bpg1 : nb1 + (cb - B) * bpg2;
    int cnt   = (cb < B) ? bpg1 : bpg2;
    uint32_t run = 0;
    for (int k = 0; k < cnt; ++k) {
        size_t idx = (size_t)(first + k) * BPG + l;
        uint32_t t = hist[idx];
        hist[idx] = run;
        run += t;
    }
    tot[j] = run;
}

__global__ __launch_bounds__(256) void scan_base(
    const uint32_t* __restrict__ tot, uint32_t* __restrict__ base, int NBINS)
{
    __shared__ uint32_t part[256];
    int t = threadIdx.x;
    int chunk = NBINS / 256;
    uint32_t s = 0;
    for (int i = 0; i < chunk; ++i) s += tot[t * chunk + i];
    part[t] = s;
    __syncthreads();
    if (t == 0) {
        uint32_t run = 0;
        for (int i = 0; i < 256; ++i) { uint32_t v = part[i]; part[i] = run; run += v; }
    }
    __syncthreads();
    uint32_t run = part[t];
    for (int i = 0; i < chunk; ++i) {
        base[t * chunk + i] = run;
        run += tot[t * chunk + i];
    }
    if (t == 255) base[NBINS] = run;
}

__global__ __launch_bounds__(BLKT) void bin_scatter_qrec(
    const uint2* __restrict__ qrec,
    int total1, int P, int n1, int n2, int B, int ppb,
    const uint32_t* __restrict__ hist, const uint32_t* __restrict__ base,
    uint2* __restrict__ records)
{
    int s = blockIdx.x * ppb;
    if (s >= P) return;
    int cb = (s < total1) ? (s / n1) : (B + (s - total1) / n2);

    __shared__ uint32_t cur[BPG];
    if (threadIdx.x < BPG)
        cur[threadIdx.x] = base[cb * BPG + threadIdx.x] +
                           hist[(size_t)blockIdx.x * BPG + threadIdx.x];
    __syncthreads();

    int e = min(s + ppb, P);
    const uint4* qr4 = (const uint4*)(qrec + (size_t)s);
    int ngrp = (e - s) >> 2;
    for (int g = threadIdx.x; g < ngrp; g += BLKT) {
        uint4 q0 = qr4[2 * g];
        uint4 q1 = qr4[2 * g + 1];
        uint2 rec[4] = {make_uint2(q0.x, q0.y), make_uint2(q0.z, q0.w),
                        make_uint2(q1.x, q1.y), make_uint2(q1.z, q1.w)};
        #pragma unroll
        for (int q = 0; q < 4; ++q) {
            uint32_t xq, yq, zq;
            unpack_rec(rec[q], xq, yq, zq);
            int rx0, rx1, ry0, ry1, rz0, rz1;
            region_range(xq, yq, zq, rx0, rx1, ry0, ry1, rz0, rz1);
            for (int aa = rx0; aa <= rx1; ++aa)
                for (int b2 = ry0; b2 <= ry1; ++b2)
                    for (int cc = rz0; cc <= rz1; ++cc) {
                        uint32_t slot =
                            atomicAdd(&cur[(aa << 5) + (b2 << 2) + cc], 1u);
                        records[slot] = rec[q];
                    }
        }
    }
}

// ---------------- pass D: per-region LDS accumulate + nontemporal 128B stores ----------------
__global__ __launch_bounds__(256) void accum_kernel(
    const uint32_t* __restrict__ base, const uint2* __restrict__ records,
    float* __restrict__ out)
{
    __shared__ float tile[16 * 16 * 32];           // 32 KB
    int bin = blockIdx.x;
    int cb = bin >> 8;
    int region = bin & 255;
    int rx = region >> 5, ry = (region >> 2) & 7, rz = region & 3;

    float4* t4 = (float4*)tile;
    for (int t = threadIdx.x; t < 2048; t += 256)
        t4[t] = make_float4(0.f, 0.f, 0.f, 0.f);
    __syncthreads();

    uint32_t s = base[bin], e = base[bin + 1];
    const float FQ = 6.103515625e-05f;             // 2^-14
    for (uint32_t r = s + threadIdx.x; r < e; r += 256) {
        uint32_t xq, yq, zq;
        unpack_rec(records[r], xq, yq, zq);
        int ix = xq >> 14, iy = yq >> 14, iz = zq >> 14;
        float fx = (float)(xq & 16383u) * FQ;
        float fy = (float)(yq & 16383u) * FQ;
        float fz = (float)(zq & 16383u) * FQ;
        float wx[2] = {1.0f - fx, fx};
        float wy[2] = {1.0f - fy, fy};
        float wz[2] = {1.0f - fz, fz};
        #pragma unroll
        for (int dx = 0; dx < 2; ++dx) {
            int cx = ix + dx;
            if ((cx >> 4) != rx) continue;
            #pragma unroll
            for (int dy = 0; dy < 2; ++dy) {
                int cy = iy + dy;
                if ((cy >> 4) != ry) continue;
                float wxy = wx[dx] * wy[dy];
                #pragma unroll
                for (int dz = 0; dz < 2; ++dz) {
                    int cz = iz + dz;
                    if ((cz >> 5) != rz) continue;
                    atomicAdd(&tile[(((cx & 15) << 4) + (cy & 15)) * 32 + (cz & 31)],
                              wxy * wz[dz]);
                }
            }
        }
    }
    __syncthreads();

    float* gout = out + (size_t)cb * R3c;
    for (int w = threadIdx.x; w < 2048; w += 256) {
        int lin = w * 4;
        int lx = lin >> 9, rem = lin & 511, ly = rem >> 5, lz = rem & 31;
        int X = rx * 16 + lx, Y = ry * 16 + ly, Z = rz * 32 + lz;
        f4v v = ((const f4v*)tile)[w];
        __builtin_nontemporal_store(v, (f4v*)&gout[((size_t)X * R + Y) * R + Z]);
    }
}

// ---------------- fallback (R1 path) ----------------
__device__ __forceinline__ void point_math_f(float px, float py, float pz,
                                             int& ix, int& iy, int& iz,
                                             float& fx, float& fy, float& fz)
{
    const float inv = 1.0f / 128.0f;
    float vx = (px * inv + 0.5f) * 128.0f;
    float vy = (py * inv + 0.5f) * 128.0f;
    float vz = (pz * inv + 0.5f) * 128.0f;
    float lx = floorf(vx), ly = floorf(vy), lz = floorf(vz);
    fx = vx - lx; fy = vy - ly; fz = vz - lz;
    ix = min(max((int)lx, 0), R - 2);
    iy = min(max((int)ly, 0), R - 2);
    iz = min(max((int)lz, 0), R - 2);
}

__global__ __launch_bounds__(256) void gridding_scatter(
    const float* __restrict__ cloud, float* __restrict__ grid,
    int total_pts, int n_per_batch)
{
    int idx = blockIdx.x * blockDim.x + threadIdx.x;
    if (idx >= total_pts) return;
    int b = idx / n_per_batch;
    const float* p = cloud + (size_t)idx * 3;
    int ix, iy, iz; float fx, fy, fz;
    point_math_f(p[0], p[1], p[2], ix, iy, iz, fx, fy, fz);
    float wx[2] = {1.0f - fx, fx};
    float wy[2] = {1.0f - fy, fy};
    float wz[2] = {1.0f - fz, fz};
    float* gb = grid + (size_t)b * R3c;
    #pragma unroll
    for (int dx = 0; dx < 2; ++dx)
        #pragma unroll
        for (int dy = 0; dy < 2; ++dy) {
            float wxy = wx[dx] * wy[dy];
            #pragma unroll
            for (int dz = 0; dz < 2; ++dz)
                atomicAdd(gb + ((size_t)(ix + dx) * R + (iy + dy)) * R + (iz + dz),
                          wxy * wz[dz]);
        }
}

extern "C" void kernel_launch(void* const* d_in, const int* in_sizes, int n_in,
                              void* d_out, int out_size, void* d_ws, size_t ws_size,
                              hipStream_t stream) {
    const float* pred = (const float*)d_in[0];
    const float* gt   = (const float*)d_in[1];
    float* out = (float*)d_out;

    int total1 = in_sizes[0] / 3;
    int total2 = in_sizes[1] / 3;
    int B  = out_size / (2 * R3c);   // 16
    int n1 = total1 / B;
    int n2 = total2 / B;
    int NBINS = 2 * B * BPG;         // 8192
    int P  = total1 + total2;
    int ppb = (P + NBLK - 1) / NBLK;

    bool fastok = (ppb % 4 == 0) && (n1 % ppb == 0) && (n2 % ppb == 0) &&
                  (n1 > 0) && (n2 > 0) && (B > 0) && (B <= MAXB) &&
                  (NBINS % 256 == 0) &&
                  (total1 % n1 == 0) && (total2 % n2 == 0);
    size_t ws_need = WS_REC + (size_t)8 * P * 8;
    if (!fastok || ws_size < ws_need) {
        hipMemsetAsync(d_out, 0, (size_t)out_size * sizeof(float), stream);
        gridding_scatter<<<(total1 + 255) / 256, 256, 0, stream>>>(pred, out, total1, n1);
        gridding_scatter<<<(total2 + 255) / 256, 256, 0, stream>>>(
            gt, out + (size_t)B * R3c, total2, n2);
        return;
    }

    uint32_t* hist  = (uint32_t*)((char*)d_ws + WS_HIST);
    uint32_t* tot   = (uint32_t*)((char*)d_ws + WS_TOT);
    uint32_t* basep = (uint32_t*)((char*)d_ws + WS_BASE);
    uint2*    qrec  = (uint2*)((char*)d_ws + WS_QREC);
    uint2*    recs  = (uint2*)((char*)d_ws + WS_REC);

    int nb1  = total1 / ppb;         // blocks for pred
    int bpg1 = n1 / ppb;             // blocks per (pred,batch)
    int bpg2 = n2 / ppb;             // blocks per (gt,batch)

    // cooperative fused path: exactly 2 groups of 4 points per thread, all
    // blocks full, scan shapes divisible
    bool coopok = fastok && (ppb == 8 * BLKT) && (P == NBLK * ppb) &&
                  (NBINS % BLKT == 0) && (NBINS <= NBLK * BLKT);
    if (coopok) {
        void* args[] = {(void*)&pred, (void*)&gt, (void*)&total1, (void*)&P,
                        (void*)&ppb, (void*)&B, (void*)&nb1, (void*)&bpg1,
                        (void*)&bpg2, (void*)&NBINS, (void*)&hist, (void*)&tot,
                        (void*)&basep, (void*)&recs};
        hipError_t err = hipLaunchCooperativeKernel(
            reinterpret_cast<const void*>(&fused_sort),
            dim3(NBLK), dim3(BLKT), args, 0, stream);
        if (err == hipSuccess) {
            accum_kernel<<<NBINS, 256, 0, stream>>>(basep, recs, out);
            return;
        }
        (void)hipGetLastError();     // clear; fall through to 5-kernel path
    }

    bin_hist_qrec<<<NBLK, BLKT, 0, stream>>>(pred, gt, total1, P, ppb, hist, qrec);
    scan1<<<(NBINS + 255) / 256, 256, 0, stream>>>(hist, tot, B, nb1, bpg1, bpg2, NBINS);
    scan_base<<<1, 256, 0, stream>>>(tot, basep, NBINS);
    bin_scatter_qrec<<<NBLK, BLKT, 0, stream>>>(qrec, total1, P, n1, n2, B, ppb,
                                                hist, basep, recs);
    accum_kernel<<<NBINS, 256, 0, stream>>>(basep, recs, out);
}

// Round 5
// 364.716 us; speedup vs baseline: 1.8896x; 1.8896x over previous
//
#include <hip/hip_runtime.h>
#include <stdint.h>

// GriddingDistance fwd, R10. R9 post-mortem: cooperative fusion ran but
// grid.sync() costs ~100us each on gfx950 (atomic spin over 512 blocks;
// fused_sort=363us @ VALUBusy 2%) -> grid-wide sync is off the table. But R9
// proved records CAN stay in registers across hist->scatter. R10 removes the
// need for the global prefix: each sort block owns a private fixed-capacity
// region (block*CAPB) of the record buffer, so scatter position = block-LOCAL
// 256-bin exclusive scan (LDS Hillis-Steele, __syncthreads only). One kernel
// fuses hist + local scan + in-register scatter; global scans, qrec (32 MB
// round-trip) and the whole bin_scatter pass are deleted. Accum reads its
// bin's records from 16 contiguous per-block segments via a tiny LDS prefix
// + binary search. 5 dispatches -> 2. Harness tax ~222us (1 GiB ws poison
// ~171 meas + 268 MB out poison ~43); accum's 268 MB store floor = 42.5us.

constexpr int R    = 128;
constexpr int R3c  = R * R * R;
constexpr int BPG  = 256;            // bins per (cloud,batch): 8 x 8 x 4 regions of 16x16x32
constexpr int NBLK = 512;            // sort blocks
constexpr int BLKT = 512;            // threads per sort block
constexpr int PPT  = 8;              // points per thread (ppb = PPT*BLKT = 4096)
constexpr int MAXB = 128;            // max batch count
constexpr int MAXSEG = 64;           // max contributing blocks per (cloud,batch)

// ws layout (byte offsets); harness ws = 1 GiB
constexpr size_t WS_HIST = 0;                 // NBLK*BPG*4 = 512 KB (counts)
constexpr size_t WS_PFX  = 1u << 20;          // NBLK*BPG*4 = 512 KB (block-local excl prefix)
constexpr size_t WS_REC  = 2u << 20;          // NBLK*CAPB*8 = 128 MB (private regions)

typedef float f4v __attribute__((ext_vector_type(4)));

// ---- quantization: v = (p/128 + 0.5)*128 == p + 64 (<=1 ulp), vq = rn(v*2^14),
// clamped so ix = vq>>14 <= 126. All binning/weights derive from vq.
__device__ __forceinline__ uint32_t quant1(float p) {
    const float S = 16384.0f;                  // 2^14
    const uint32_t QMAX = (126u << 14) | 16383u;
    float v = p + 64.0f;
    return min(__float2uint_rn(fmaxf(v, 0.0f) * S), QMAX);
}

__device__ __forceinline__ uint2 pack_rec(uint32_t xq, uint32_t yq, uint32_t zq) {
    return make_uint2(xq | (yq << 21), (yq >> 11) | (zq << 10));
}
__device__ __forceinline__ void unpack_rec(uint2 r, uint32_t& xq, uint32_t& yq, uint32_t& zq) {
    xq = r.x & 0x1FFFFFu;
    yq = (r.x >> 21) | ((r.y & 0x3FFu) << 11);
    zq = (r.y >> 10) & 0x1FFFFFu;
}

// local (within cloud,batch) region bounds from quantized cell coords
__device__ __forceinline__ void region_range(uint32_t xq, uint32_t yq, uint32_t zq,
                                             int& rx0, int& rx1, int& ry0, int& ry1,
                                             int& rz0, int& rz1)
{
    int ix = xq >> 14, iy = yq >> 14, iz = zq >> 14;
    rx0 = ix >> 4; rx1 = (ix + 1) >> 4;
    ry0 = iy >> 4; ry1 = (iy + 1) >> 4;
    rz0 = iz >> 5; rz1 = (iz + 1) >> 5;
}

// ======== pass A: fused hist + block-local scan + in-register scatter ========
// preconditions (host-checked): ppb == PPT*BLKT, every block fully inside one
// (cloud,batch), all blocks full.
__global__ __launch_bounds__(BLKT) void sort_local(
    const float* __restrict__ pred, const float* __restrict__ gt,
    int total1, int capb,
    uint32_t* __restrict__ hist, uint32_t* __restrict__ pfxg,
    uint2* __restrict__ records)
{
    __shared__ uint32_t h[BPG];                    // counts
    __shared__ uint32_t px[BPG];                   // scan / cursors
    if (threadIdx.x < BPG) h[threadIdx.x] = 0;
    __syncthreads();

    const int ppb = PPT * BLKT;
    int s = blockIdx.x * ppb;
    bool isgt = (s >= total1);
    const float4* src4 = (const float4*)(isgt ? gt + (size_t)(s - total1) * 3
                                              : pred + (size_t)s * 3);
    // ---- phase 1: quantize, count; records stay in registers ----
    uint2 lrec[PPT / 4][4];
    #pragma unroll
    for (int it = 0; it < PPT / 4; ++it) {
        int g = threadIdx.x + it * BLKT;           // 4-point group index
        float4 a  = src4[g * 3 + 0];
        float4 b4 = src4[g * 3 + 1];
        float4 c4 = src4[g * 3 + 2];
        float xs[4] = {a.x, a.w, b4.z, c4.y};
        float ys[4] = {a.y, b4.x, b4.w, c4.z};
        float zs[4] = {a.z, b4.y, c4.x, c4.w};
        #pragma unroll
        for (int q = 0; q < 4; ++q) {
            uint32_t xq = quant1(xs[q]), yq = quant1(ys[q]), zq = quant1(zs[q]);
            lrec[it][q] = pack_rec(xq, yq, zq);
            int rx0, rx1, ry0, ry1, rz0, rz1;
            region_range(xq, yq, zq, rx0, rx1, ry0, ry1, rz0, rz1);
            for (int aa = rx0; aa <= rx1; ++aa)
                for (int bb = ry0; bb <= ry1; ++bb)
                    for (int cc = rz0; cc <= rz1; ++cc)
                        atomicAdd(&h[(aa << 5) + (bb << 2) + cc], 1u);
        }
    }
    __syncthreads();

    // ---- phase 2: block-local exclusive scan over the 256 bins ----
    if (threadIdx.x < BPG) px[threadIdx.x] = h[threadIdx.x];
    __syncthreads();
    #pragma unroll
    for (int off = 1; off < BPG; off <<= 1) {
        uint32_t v = 0;
        if (threadIdx.x < BPG && threadIdx.x >= (uint32_t)off)
            v = px[threadIdx.x - off];
        __syncthreads();
        if (threadIdx.x < BPG) px[threadIdx.x] += v;
        __syncthreads();
    }
    if (threadIdx.x < BPG) {
        uint32_t excl = px[threadIdx.x] - h[threadIdx.x];
        hist[(size_t)blockIdx.x * BPG + threadIdx.x] = h[threadIdx.x];
        pfxg[(size_t)blockIdx.x * BPG + threadIdx.x] = excl;
        px[threadIdx.x] = excl;                    // reuse as bump cursor
    }
    __syncthreads();

    // ---- phase 3: scatter in-register records into the private region ----
    uint2* rbase = records + (size_t)blockIdx.x * capb;
    #pragma unroll
    for (int it = 0; it < PPT / 4; ++it) {
        #pragma unroll
        for (int q = 0; q < 4; ++q) {
            uint2 rec = lrec[it][q];
            uint32_t xq, yq, zq;
            unpack_rec(rec, xq, yq, zq);
            int rx0, rx1, ry0, ry1, rz0, rz1;
            region_range(xq, yq, zq, rx0, rx1, ry0, ry1, rz0, rz1);
            for (int aa = rx0; aa <= rx1; ++aa)
                for (int bb = ry0; bb <= ry1; ++bb)
                    for (int cc = rz0; cc <= rz1; ++cc) {
                        uint32_t slot = atomicAdd(&px[(aa << 5) + (bb << 2) + cc], 1u);
                        rbase[slot] = rec;
                    }
        }
    }
}

// ======== pass B: per-region LDS accumulate over per-block segments ========
__global__ __launch_bounds__(256) void accum_seg(
    const uint32_t* __restrict__ hist, const uint32_t* __restrict__ pfxg,
    const uint2* __restrict__ records, float* __restrict__ out,
    int B, int nb1, int bpg1, int bpg2, int capb)
{
    __shared__ float tile[16 * 16 * 32];           // 32 KB
    __shared__ uint32_t sOff[MAXSEG + 1];          // cumulative counts
    __shared__ uint32_t sStart[MAXSEG];            // per-segment start offset
    int bin = blockIdx.x;
    int cb = bin >> 8;
    int l  = bin & 255;
    int rx = l >> 5, ry = (l >> 2) & 7, rz = l & 3;

    int first = (cb < B) ? cb * bpg1 : nb1 + (cb - B) * bpg2;
    int cnt   = (cb < B) ? bpg1 : bpg2;

    float4* t4 = (float4*)tile;
    for (int t = threadIdx.x; t < 2048; t += 256)
        t4[t] = make_float4(0.f, 0.f, 0.f, 0.f);
    if (threadIdx.x < (uint32_t)cnt) {
        sStart[threadIdx.x] = pfxg[(size_t)(first + threadIdx.x) * BPG + l];
        sOff[threadIdx.x]   = hist[(size_t)(first + threadIdx.x) * BPG + l];
    }
    __syncthreads();
    if (threadIdx.x == 0) {
        uint32_t run = 0;
        for (int k = 0; k < cnt; ++k) { uint32_t c = sOff[k]; sOff[k] = run; run += c; }
        sOff[cnt] = run;
    }
    __syncthreads();

    uint32_t total = sOff[cnt];
    const float FQ = 6.103515625e-05f;             // 2^-14
    for (uint32_t r = threadIdx.x; r < total; r += 256) {
        // largest k with sOff[k] <= r
        int lo = 0, hi = cnt - 1;
        while (lo < hi) {
            int mid = (lo + hi + 1) >> 1;
            if (sOff[mid] <= r) lo = mid; else hi = mid - 1;
        }
        uint2 rc = records[(size_t)(first + lo) * capb + sStart[lo] + (r - sOff[lo])];
        uint32_t xq, yq, zq;
        unpack_rec(rc, xq, yq, zq);
        int ix = xq >> 14, iy = yq >> 14, iz = zq >> 14;
        float fx = (float)(xq & 16383u) * FQ;
        float fy = (float)(yq & 16383u) * FQ;
        float fz = (float)(zq & 16383u) * FQ;
        float wx[2] = {1.0f - fx, fx};
        float wy[2] = {1.0f - fy, fy};
        float wz[2] = {1.0f - fz, fz};
        #pragma unroll
        for (int dx = 0; dx < 2; ++dx) {
            int cx = ix + dx;
            if ((cx >> 4) != rx) continue;
            #pragma unroll
            for (int dy = 0; dy < 2; ++dy) {
                int cy = iy + dy;
                if ((cy >> 4) != ry) continue;
                float wxy = wx[dx] * wy[dy];
                #pragma unroll
                for (int dz = 0; dz < 2; ++dz) {
                    int cz = iz + dz;
                    if ((cz >> 5) != rz) continue;
                    atomicAdd(&tile[(((cx & 15) << 4) + (cy & 15)) * 32 + (cz & 31)],
                              wxy * wz[dz]);
                }
            }
        }
    }
    __syncthreads();

    // full region store: each (X,Y) z-row is 32 floats = one 128 B line
    float* gout = out + (size_t)cb * R3c;
    for (int w = threadIdx.x; w < 2048; w += 256) {
        int lin = w * 4;
        int lx = lin >> 9, rem = lin & 511, ly = rem >> 5, lz = rem & 31;
        int X = rx * 16 + lx, Y = ry * 16 + ly, Z = rz * 32 + lz;
        f4v v = ((const f4v*)tile)[w];
        __builtin_nontemporal_store(v, (f4v*)&gout[((size_t)X * R + Y) * R + Z]);
    }
}

// ---------------- fallback (R1 path) ----------------
__device__ __forceinline__ void point_math_f(float px, float py, float pz,
                                             int& ix, int& iy, int& iz,
                                             float& fx, float& fy, float& fz)
{
    const float inv = 1.0f / 128.0f;
    float vx = (px * inv + 0.5f) * 128.0f;
    float vy = (py * inv + 0.5f) * 128.0f;
    float vz = (pz * inv + 0.5f) * 128.0f;
    float lx = floorf(vx), ly = floorf(vy), lz = floorf(vz);
    fx = vx - lx; fy = vy - ly; fz = vz - lz;
    ix = min(max((int)lx, 0), R - 2);
    iy = min(max((int)ly, 0), R - 2);
    iz = min(max((int)lz, 0), R - 2);
}

__global__ __launch_bounds__(256) void gridding_scatter(
    const float* __restrict__ cloud, float* __restrict__ grid,
    int total_pts, int n_per_batch)
{
    int idx = blockIdx.x * blockDim.x + threadIdx.x;
    if (idx >= total_pts) return;
    int b = idx / n_per_batch;
    const float* p = cloud + (size_t)idx * 3;
    int ix, iy, iz; float fx, fy, fz;
    point_math_f(p[0], p[1], p[2], ix, iy, iz, fx, fy, fz);
    float wx[2] = {1.0f - fx, fx};
    float wy[2] = {1.0f - fy, fy};
    float wz[2] = {1.0f - fz, fz};
    float* gb = grid + (size_t)b * R3c;
    #pragma unroll
    for (int dx = 0; dx < 2; ++dx)
        #pragma unroll
        for (int dy = 0; dy < 2; ++dy) {
            float wxy = wx[dx] * wy[dy];
            #pragma unroll
            for (int dz = 0; dz < 2; ++dz)
                atomicAdd(gb + ((size_t)(ix + dx) * R + (iy + dy)) * R + (iz + dz),
                          wxy * wz[dz]);
        }
}

extern "C" void kernel_launch(void* const* d_in, const int* in_sizes, int n_in,
                              void* d_out, int out_size, void* d_ws, size_t ws_size,
                              hipStream_t stream) {
    const float* pred = (const float*)d_in[0];
    const float* gt   = (const float*)d_in[1];
    float* out = (float*)d_out;

    int total1 = in_sizes[0] / 3;
    int total2 = in_sizes[1] / 3;
    int B  = out_size / (2 * R3c);   // 16
    int n1 = (B > 0) ? total1 / B : 0;
    int n2 = (B > 0) ? total2 / B : 0;
    int NBINS = 2 * B * BPG;         // 8192
    int P  = total1 + total2;
    int ppb = PPT * BLKT;            // 4096 (fixed per-block point count)

    int capb = 8 * ppb;              // worst-case records per block
    size_t ws_need = WS_REC + (size_t)NBLK * capb * 8;

    // strict fast path: all blocks full, each inside one (cloud,batch)
    bool fastok = (B > 0) && (B <= MAXB) && (n1 > 0) && (n2 > 0) &&
                  (total1 == B * n1) && (total2 == B * n2) &&
                  (P == NBLK * ppb) &&
                  (n1 % ppb == 0) && (n2 % ppb == 0) &&
                  (n1 / ppb <= MAXSEG) && (n2 / ppb <= MAXSEG) &&
                  (ws_size >= ws_need);
    if (!fastok) {
        hipMemsetAsync(d_out, 0, (size_t)out_size * sizeof(float), stream);
        gridding_scatter<<<(total1 + 255) / 256, 256, 0, stream>>>(pred, out, total1, n1);
        gridding_scatter<<<(total2 + 255) / 256, 256, 0, stream>>>(
            gt, out + (size_t)B * R3c, total2, n2);
        return;
    }

    uint32_t* hist = (uint32_t*)((char*)d_ws + WS_HIST);
    uint32_t* pfxg = (uint32_t*)((char*)d_ws + WS_PFX);
    uint2*    recs = (uint2*)((char*)d_ws + WS_REC);

    int nb1  = total1 / ppb;         // blocks for pred
    int bpg1 = n1 / ppb;             // blocks per (pred,batch)
    int bpg2 = n2 / ppb;             // blocks per (gt,batch)

    sort_local<<<NBLK, BLKT, 0, stream>>>(pred, gt, total1, capb, hist, pfxg, recs);
    accum_seg<<<NBINS, 256, 0, stream>>>(hist, pfxg, recs, out,
                                         B, nb1, bpg1, bpg2, capb);
}

// Round 6
// 356.948 us; speedup vs baseline: 1.9307x; 1.0218x over previous
//
#include <hip/hip_runtime.h>
#include <stdint.h>

// GriddingDistance fwd, R11. R10 (364.7us) proved the 2-dispatch structure:
// block-private record regions kill the global scan without grid.sync (R9:
// grid.sync ~100us each on gfx950 - never again). Accounting: ~226us harness
// poison tax + ~139us ours vs ~55us floor. R11 micro-attacks both kernels:
// (1) sort: records bump-scattered into a 32KB LDS stage then DUMPED
// COALESCED (R10 scattered 2.44M x 8B stores = ~64 line-splits per wave);
// PPT 8->4, NBLK 512->1024 so the stage fits (cap 4096 vs ~2375 avg; direct-
// scatter fallback branch if a block ever overflows). (2) accum: 512 threads
// (doubles init/store issue rate; store drain of 32KB/block is its long
// pole), still 4 blocks/CU at 32.5KB LDS -> 32 waves/CU.

constexpr int R    = 128;
constexpr int R3c  = R * R * R;
constexpr int BPG  = 256;            // bins per (cloud,batch): 8 x 8 x 4 regions of 16x16x32
constexpr int NBLK = 1024;           // sort blocks
constexpr int BLKT = 512;            // threads per sort block
constexpr int PPT  = 4;              // points per thread (ppb = PPT*BLKT = 2048)
constexpr int STCAP = 4096;          // LDS record-stage capacity (32 KB)
constexpr int ABLK = 512;            // accum threads
constexpr int MAXB = 128;            // max batch count
constexpr int MAXSEG = 64;           // max contributing blocks per (cloud,batch)

// ws layout (byte offsets); harness ws = 1 GiB
constexpr size_t WS_HIST = 0;                 // NBLK*BPG*4 = 1 MB (counts)
constexpr size_t WS_PFX  = 1u << 20;          // NBLK*BPG*4 = 1 MB (block-local excl prefix)
constexpr size_t WS_REC  = 2u << 20;          // NBLK*capb*8 = 128 MB (private regions)

typedef float f4v __attribute__((ext_vector_type(4)));

// ---- quantization: v = (p/128 + 0.5)*128 == p + 64 (<=1 ulp), vq = rn(v*2^14),
// clamped so ix = vq>>14 <= 126. All binning/weights derive from vq.
__device__ __forceinline__ uint32_t quant1(float p) {
    const float S = 16384.0f;                  // 2^14
    const uint32_t QMAX = (126u << 14) | 16383u;
    float v = p + 64.0f;
    return min(__float2uint_rn(fmaxf(v, 0.0f) * S), QMAX);
}

__device__ __forceinline__ uint2 pack_rec(uint32_t xq, uint32_t yq, uint32_t zq) {
    return make_uint2(xq | (yq << 21), (yq >> 11) | (zq << 10));
}
__device__ __forceinline__ void unpack_rec(uint2 r, uint32_t& xq, uint32_t& yq, uint32_t& zq) {
    xq = r.x & 0x1FFFFFu;
    yq = (r.x >> 21) | ((r.y & 0x3FFu) << 11);
    zq = (r.y >> 10) & 0x1FFFFFu;
}

// local (within cloud,batch) region bounds from quantized cell coords
__device__ __forceinline__ void region_range(uint32_t xq, uint32_t yq, uint32_t zq,
                                             int& rx0, int& rx1, int& ry0, int& ry1,
                                             int& rz0, int& rz1)
{
    int ix = xq >> 14, iy = yq >> 14, iz = zq >> 14;
    rx0 = ix >> 4; rx1 = (ix + 1) >> 4;
    ry0 = iy >> 4; ry1 = (iy + 1) >> 4;
    rz0 = iz >> 5; rz1 = (iz + 1) >> 5;
}

// ======== pass A: hist + block-local scan + LDS-staged coalesced scatter ========
// preconditions (host-checked): every block fully inside one (cloud,batch),
// all blocks full (ppb points each).
__global__ __launch_bounds__(BLKT) void sort_local(
    const float* __restrict__ pred, const float* __restrict__ gt,
    int total1, int capb,
    uint32_t* __restrict__ hist, uint32_t* __restrict__ pfxg,
    uint2* __restrict__ records)
{
    __shared__ uint32_t h[BPG];                    // counts
    __shared__ uint32_t px[BPG];                   // scan / cursors
    __shared__ uint2 stg[STCAP];                   // 32 KB record stage
    __shared__ uint32_t sT;                        // block record total
    if (threadIdx.x < BPG) h[threadIdx.x] = 0;
    __syncthreads();

    const int ppb = PPT * BLKT;
    int s = blockIdx.x * ppb;
    bool isgt = (s >= total1);
    const float4* src4 = (const float4*)(isgt ? gt + (size_t)(s - total1) * 3
                                              : pred + (size_t)s * 3);
    // ---- phase 1: quantize, count; records stay in registers ----
    int g = threadIdx.x;                           // 4-point group index
    float4 a  = src4[g * 3 + 0];
    float4 b4 = src4[g * 3 + 1];
    float4 c4 = src4[g * 3 + 2];
    float xs[4] = {a.x, a.w, b4.z, c4.y};
    float ys[4] = {a.y, b4.x, b4.w, c4.z};
    float zs[4] = {a.z, b4.y, c4.x, c4.w};
    uint2 lrec[4];
    #pragma unroll
    for (int q = 0; q < 4; ++q) {
        uint32_t xq = quant1(xs[q]), yq = quant1(ys[q]), zq = quant1(zs[q]);
        lrec[q] = pack_rec(xq, yq, zq);
        int rx0, rx1, ry0, ry1, rz0, rz1;
        region_range(xq, yq, zq, rx0, rx1, ry0, ry1, rz0, rz1);
        for (int aa = rx0; aa <= rx1; ++aa)
            for (int bb = ry0; bb <= ry1; ++bb)
                for (int cc = rz0; cc <= rz1; ++cc)
                    atomicAdd(&h[(aa << 5) + (bb << 2) + cc], 1u);
    }
    __syncthreads();

    // ---- phase 2: block-local exclusive scan over the 256 bins ----
    if (threadIdx.x < BPG) px[threadIdx.x] = h[threadIdx.x];
    __syncthreads();
    #pragma unroll
    for (int off = 1; off < BPG; off <<= 1) {
        uint32_t v = 0;
        if (threadIdx.x < BPG && threadIdx.x >= (uint32_t)off)
            v = px[threadIdx.x - off];
        __syncthreads();
        if (threadIdx.x < BPG) px[threadIdx.x] += v;
        __syncthreads();
    }
    if (threadIdx.x == BPG - 1) sT = px[BPG - 1];  // inclusive total
    if (threadIdx.x < BPG) {
        uint32_t excl = px[threadIdx.x] - h[threadIdx.x];
        hist[(size_t)blockIdx.x * BPG + threadIdx.x] = h[threadIdx.x];
        pfxg[(size_t)blockIdx.x * BPG + threadIdx.x] = excl;
        px[threadIdx.x] = excl;                    // reuse as bump cursor
    }
    __syncthreads();

    // ---- phase 3: scatter to LDS stage, then coalesced dump ----
    uint2* rbase = records + (size_t)blockIdx.x * capb;
    uint32_t T = sT;
    if (T <= (uint32_t)STCAP) {
        #pragma unroll
        for (int q = 0; q < 4; ++q) {
            uint2 rec = lrec[q];
            uint32_t xq, yq, zq;
            unpack_rec(rec, xq, yq, zq);
            int rx0, rx1, ry0, ry1, rz0, rz1;
            region_range(xq, yq, zq, rx0, rx1, ry0, ry1, rz0, rz1);
            for (int aa = rx0; aa <= rx1; ++aa)
                for (int bb = ry0; bb <= ry1; ++bb)
                    for (int cc = rz0; cc <= rz1; ++cc) {
                        uint32_t slot = atomicAdd(&px[(aa << 5) + (bb << 2) + cc], 1u);
                        stg[slot] = rec;
                    }
        }
        __syncthreads();
        for (uint32_t i = threadIdx.x; i < T; i += BLKT)
            rbase[i] = stg[i];
    } else {
        // overflow fallback (cannot trigger for near-uniform data): direct scatter
        #pragma unroll
        for (int q = 0; q < 4; ++q) {
            uint2 rec = lrec[q];
            uint32_t xq, yq, zq;
            unpack_rec(rec, xq, yq, zq);
            int rx0, rx1, ry0, ry1, rz0, rz1;
            region_range(xq, yq, zq, rx0, rx1, ry0, ry1, rz0, rz1);
            for (int aa = rx0; aa <= rx1; ++aa)
                for (int bb = ry0; bb <= ry1; ++bb)
                    for (int cc = rz0; cc <= rz1; ++cc) {
                        uint32_t slot = atomicAdd(&px[(aa << 5) + (bb << 2) + cc], 1u);
                        rbase[slot] = rec;
                    }
        }
    }
}

// ======== pass B: per-region LDS accumulate over per-block segments ========
__global__ __launch_bounds__(ABLK) void accum_seg(
    const uint32_t* __restrict__ hist, const uint32_t* __restrict__ pfxg,
    const uint2* __restrict__ records, float* __restrict__ out,
    int B, int nb1, int bpg1, int bpg2, int capb)
{
    __shared__ float tile[16 * 16 * 32];           // 32 KB
    __shared__ uint32_t sOff[MAXSEG + 1];          // cumulative counts
    __shared__ uint32_t sStart[MAXSEG];            // per-segment start offset
    int bin = blockIdx.x;
    int cb = bin >> 8;
    int l  = bin & 255;
    int rx = l >> 5, ry = (l >> 2) & 7, rz = l & 3;

    int first = (cb < B) ? cb * bpg1 : nb1 + (cb - B) * bpg2;
    int cnt   = (cb < B) ? bpg1 : bpg2;

    float4* t4 = (float4*)tile;
    for (int t = threadIdx.x; t < 2048; t += ABLK)
        t4[t] = make_float4(0.f, 0.f, 0.f, 0.f);
    if (threadIdx.x < (uint32_t)cnt) {
        sStart[threadIdx.x] = pfxg[(size_t)(first + threadIdx.x) * BPG + l];
        sOff[threadIdx.x]   = hist[(size_t)(first + threadIdx.x) * BPG + l];
    }
    __syncthreads();
    if (threadIdx.x == 0) {
        uint32_t run = 0;
        for (int k = 0; k < cnt; ++k) { uint32_t c = sOff[k]; sOff[k] = run; run += c; }
        sOff[cnt] = run;
    }
    __syncthreads();

    uint32_t total = sOff[cnt];
    const float FQ = 6.103515625e-05f;             // 2^-14
    for (uint32_t r = threadIdx.x; r < total; r += ABLK) {
        // largest k with sOff[k] <= r
        int lo = 0, hi = cnt - 1;
        while (lo < hi) {
            int mid = (lo + hi + 1) >> 1;
            if (sOff[mid] <= r) lo = mid; else hi = mid - 1;
        }
        uint2 rc = records[(size_t)(first + lo) * capb + sStart[lo] + (r - sOff[lo])];
        uint32_t xq, yq, zq;
        unpack_rec(rc, xq, yq, zq);
        int ix = xq >> 14, iy = yq >> 14, iz = zq >> 14;
        float fx = (float)(xq & 16383u) * FQ;
        float fy = (float)(yq & 16383u) * FQ;
        float fz = (float)(zq & 16383u) * FQ;
        float wx[2] = {1.0f - fx, fx};
        float wy[2] = {1.0f - fy, fy};
        float wz[2] = {1.0f - fz, fz};
        #pragma unroll
        for (int dx = 0; dx < 2; ++dx) {
            int cx = ix + dx;
            if ((cx >> 4) != rx) continue;
            #pragma unroll
            for (int dy = 0; dy < 2; ++dy) {
                int cy = iy + dy;
                if ((cy >> 4) != ry) continue;
                float wxy = wx[dx] * wy[dy];
                #pragma unroll
                for (int dz = 0; dz < 2; ++dz) {
                    int cz = iz + dz;
                    if ((cz >> 5) != rz) continue;
                    atomicAdd(&tile[(((cx & 15) << 4) + (cy & 15)) * 32 + (cz & 31)],
                              wxy * wz[dz]);
                }
            }
        }
    }
    __syncthreads();

    // full region store: each (X,Y) z-row is 32 floats = one 128 B line
    float* gout = out + (size_t)cb * R3c;
    for (int w = threadIdx.x; w < 2048; w += ABLK) {
        int lin = w * 4;
        int lx = lin >> 9, rem = lin & 511, ly = rem >> 5, lz = rem & 31;
        int X = rx * 16 + lx, Y = ry * 16 + ly, Z = rz * 32 + lz;
        f4v v = ((const f4v*)tile)[w];
        __builtin_nontemporal_store(v, (f4v*)&gout[((size_t)X * R + Y) * R + Z]);
    }
}

// ---------------- fallback (R1 path) ----------------
__device__ __forceinline__ void point_math_f(float px, float py, float pz,
                                             int& ix, int& iy, int& iz,
                                             float& fx, float& fy, float& fz)
{
    const float inv = 1.0f / 128.0f;
    float vx = (px * inv + 0.5f) * 128.0f;
    float vy = (py * inv + 0.5f) * 128.0f;
    float vz = (pz * inv + 0.5f) * 128.0f;
    float lx = floorf(vx), ly = floorf(vy), lz = floorf(vz);
    fx = vx - lx; fy = vy - ly; fz = vz - lz;
    ix = min(max((int)lx, 0), R - 2);
    iy = min(max((int)ly, 0), R - 2);
    iz = min(max((int)lz, 0), R - 2);
}

__global__ __launch_bounds__(256) void gridding_scatter(
    const float* __restrict__ cloud, float* __restrict__ grid,
    int total_pts, int n_per_batch)
{
    int idx = blockIdx.x * blockDim.x + threadIdx.x;
    if (idx >= total_pts) return;
    int b = idx / n_per_batch;
    const float* p = cloud + (size_t)idx * 3;
    int ix, iy, iz; float fx, fy, fz;
    point_math_f(p[0], p[1], p[2], ix, iy, iz, fx, fy, fz);
    float wx[2] = {1.0f - fx, fx};
    float wy[2] = {1.0f - fy, fy};
    float wz[2] = {1.0f - fz, fz};
    float* gb = grid + (size_t)b * R3c;
    #pragma unroll
    for (int dx = 0; dx < 2; ++dx)
        #pragma unroll
        for (int dy = 0; dy < 2; ++dy) {
            float wxy = wx[dx] * wy[dy];
            #pragma unroll
            for (int dz = 0; dz < 2; ++dz)
                atomicAdd(gb + ((size_t)(ix + dx) * R + (iy + dy)) * R + (iz + dz),
                          wxy * wz[dz]);
        }
}

extern "C" void kernel_launch(void* const* d_in, const int* in_sizes, int n_in,
                              void* d_out, int out_size, void* d_ws, size_t ws_size,
                              hipStream_t stream) {
    const float* pred = (const float*)d_in[0];
    const float* gt   = (const float*)d_in[1];
    float* out = (float*)d_out;

    int total1 = in_sizes[0] / 3;
    int total2 = in_sizes[1] / 3;
    int B  = out_size / (2 * R3c);   // 16
    int n1 = (B > 0) ? total1 / B : 0;
    int n2 = (B > 0) ? total2 / B : 0;
    int P  = total1 + total2;
    int ppb = PPT * BLKT;            // 2048 (fixed per-block point count)

    int capb = 8 * ppb;              // worst-case records per block (16384)
    size_t ws_need = WS_REC + (size_t)NBLK * capb * 8;   // ~130 MB

    // strict fast path: all blocks full, each inside one (cloud,batch)
    bool fastok = (B > 0) && (B <= MAXB) && (n1 > 0) && (n2 > 0) &&
                  (total1 == B * n1) && (total2 == B * n2) &&
                  (P == NBLK * ppb) &&
                  (n1 % ppb == 0) && (n2 % ppb == 0) &&
                  (n1 / ppb <= MAXSEG) && (n2 / ppb <= MAXSEG) &&
                  (ws_size >= ws_need);
    if (!fastok) {
        hipMemsetAsync(d_out, 0, (size_t)out_size * sizeof(float), stream);
        gridding_scatter<<<(total1 + 255) / 256, 256, 0, stream>>>(pred, out, total1, n1);
        gridding_scatter<<<(total2 + 255) / 256, 256, 0, stream>>>(
            gt, out + (size_t)B * R3c, total2, n2);
        return;
    }

    uint32_t* hist = (uint32_t*)((char*)d_ws + WS_HIST);
    uint32_t* pfxg = (uint32_t*)((char*)d_ws + WS_PFX);
    uint2*    recs = (uint2*)((char*)d_ws + WS_REC);

    int nb1  = total1 / ppb;         // blocks for pred (512)
    int bpg1 = n1 / ppb;             // blocks per (pred,batch) (32)
    int bpg2 = n2 / ppb;             // blocks per (gt,batch)   (32)
    int NBINS = 2 * B * BPG;         // 8192

    sort_local<<<NBLK, BLKT, 0, stream>>>(pred, gt, total1, capb, hist, pfxg, recs);
    accum_seg<<<NBINS, ABLK, 0, stream>>>(hist, pfxg, recs, out,
                                          B, nb1, bpg1, bpg2, capb);
}

// Round 7
// 356.231 us; speedup vs baseline: 1.9346x; 1.0020x over previous
//
#include <hip/hip_runtime.h>
#include <stdint.h>

// GriddingDistance fwd, R12 (consolidation). R11 = 356.9us. Ledger: ~230us
// unattackable harness tax (1 GiB ws poison ~170 meas + 268 MB out poison
// ~43 + input restore ~16) + ~127us ours vs ~55-65us floor (25 MB points +
// 19.5 MB records x2 + 268 MB output store @6.3 TB/s + launch gaps). R12
// removes the last named small costs: (1) sort's 16-barrier Hillis-Steele
// -> wave shfl scan (2 barriers); (2) uint4 LDS->global record dump (16B/
// lane); (3) accum record loop 2x unrolled for MLP (loads+searches issued
// before the dependent LDS atomics). If neutral: structure is at its
// practical floor (declare roofline).

constexpr int R    = 128;
constexpr int R3c  = R * R * R;
constexpr int BPG  = 256;            // bins per (cloud,batch): 8 x 8 x 4 regions of 16x16x32
constexpr int NBLK = 1024;           // sort blocks
constexpr int BLKT = 512;            // threads per sort block
constexpr int PPT  = 4;              // points per thread (ppb = PPT*BLKT = 2048)
constexpr int STCAP = 4096;          // LDS record-stage capacity (32 KB)
constexpr int ABLK = 512;            // accum threads
constexpr int MAXB = 128;            // max batch count
constexpr int MAXSEG = 64;           // max contributing blocks per (cloud,batch)

// ws layout (byte offsets); harness ws = 1 GiB
constexpr size_t WS_HIST = 0;                 // NBLK*BPG*4 = 1 MB (counts)
constexpr size_t WS_PFX  = 1u << 20;          // NBLK*BPG*4 = 1 MB (block-local excl prefix)
constexpr size_t WS_REC  = 2u << 20;          // NBLK*capb*8 = 128 MB (private regions)

typedef float f4v __attribute__((ext_vector_type(4)));

// ---- quantization: v = (p/128 + 0.5)*128 == p + 64 (<=1 ulp), vq = rn(v*2^14),
// clamped so ix = vq>>14 <= 126. All binning/weights derive from vq.
__device__ __forceinline__ uint32_t quant1(float p) {
    const float S = 16384.0f;                  // 2^14
    const uint32_t QMAX = (126u << 14) | 16383u;
    float v = p + 64.0f;
    return min(__float2uint_rn(fmaxf(v, 0.0f) * S), QMAX);
}

__device__ __forceinline__ uint2 pack_rec(uint32_t xq, uint32_t yq, uint32_t zq) {
    return make_uint2(xq | (yq << 21), (yq >> 11) | (zq << 10));
}
__device__ __forceinline__ void unpack_rec(uint2 r, uint32_t& xq, uint32_t& yq, uint32_t& zq) {
    xq = r.x & 0x1FFFFFu;
    yq = (r.x >> 21) | ((r.y & 0x3FFu) << 11);
    zq = (r.y >> 10) & 0x1FFFFFu;
}

// local (within cloud,batch) region bounds from quantized cell coords
__device__ __forceinline__ void region_range(uint32_t xq, uint32_t yq, uint32_t zq,
                                             int& rx0, int& rx1, int& ry0, int& ry1,
                                             int& rz0, int& rz1)
{
    int ix = xq >> 14, iy = yq >> 14, iz = zq >> 14;
    rx0 = ix >> 4; rx1 = (ix + 1) >> 4;
    ry0 = iy >> 4; ry1 = (iy + 1) >> 4;
    rz0 = iz >> 5; rz1 = (iz + 1) >> 5;
}

// ======== pass A: hist + wave-scan + LDS-staged coalesced scatter ========
// preconditions (host-checked): every block fully inside one (cloud,batch),
// all blocks full (ppb points each).
__global__ __launch_bounds__(BLKT) void sort_local(
    const float* __restrict__ pred, const float* __restrict__ gt,
    int total1, int capb,
    uint32_t* __restrict__ hist, uint32_t* __restrict__ pfxg,
    uint2* __restrict__ records)
{
    __shared__ uint32_t h[BPG];                    // counts
    __shared__ uint32_t px[BPG];                   // cursors
    __shared__ __align__(16) uint2 stg[STCAP];     // 32 KB record stage
    __shared__ uint32_t wsum[4];                   // per-wave scan sums
    __shared__ uint32_t sT;                        // block record total
    if (threadIdx.x < BPG) h[threadIdx.x] = 0;
    __syncthreads();

    const int ppb = PPT * BLKT;
    int s = blockIdx.x * ppb;
    bool isgt = (s >= total1);
    const float4* src4 = (const float4*)(isgt ? gt + (size_t)(s - total1) * 3
                                              : pred + (size_t)s * 3);
    // ---- phase 1: quantize, count; records stay in registers ----
    int g = threadIdx.x;                           // 4-point group index
    float4 a  = src4[g * 3 + 0];
    float4 b4 = src4[g * 3 + 1];
    float4 c4 = src4[g * 3 + 2];
    float xs[4] = {a.x, a.w, b4.z, c4.y};
    float ys[4] = {a.y, b4.x, b4.w, c4.z};
    float zs[4] = {a.z, b4.y, c4.x, c4.w};
    uint2 lrec[4];
    #pragma unroll
    for (int q = 0; q < 4; ++q) {
        uint32_t xq = quant1(xs[q]), yq = quant1(ys[q]), zq = quant1(zs[q]);
        lrec[q] = pack_rec(xq, yq, zq);
        int rx0, rx1, ry0, ry1, rz0, rz1;
        region_range(xq, yq, zq, rx0, rx1, ry0, ry1, rz0, rz1);
        for (int aa = rx0; aa <= rx1; ++aa)
            for (int bb = ry0; bb <= ry1; ++bb)
                for (int cc = rz0; cc <= rz1; ++cc)
                    atomicAdd(&h[(aa << 5) + (bb << 2) + cc], 1u);
    }
    __syncthreads();

    // ---- phase 2: 256-bin exclusive scan via intra-wave shfl (waves 0-3) ----
    uint32_t cntv = 0, incl = 0;
    if (threadIdx.x < BPG) {
        cntv = h[threadIdx.x];
        incl = cntv;
        #pragma unroll
        for (int off = 1; off < 64; off <<= 1) {
            uint32_t v = __shfl_up(incl, off, 64);
            if ((threadIdx.x & 63) >= off) incl += v;
        }
        if ((threadIdx.x & 63) == 63) wsum[threadIdx.x >> 6] = incl;
    }
    __syncthreads();
    if (threadIdx.x < BPG) {
        int w = threadIdx.x >> 6;
        uint32_t add = 0;
        #pragma unroll
        for (int k = 0; k < 3; ++k) if (k < w) add += wsum[k];
        incl += add;
        uint32_t excl = incl - cntv;
        hist[(size_t)blockIdx.x * BPG + threadIdx.x] = cntv;
        pfxg[(size_t)blockIdx.x * BPG + threadIdx.x] = excl;
        px[threadIdx.x] = excl;                    // bump cursor
        if (threadIdx.x == BPG - 1) sT = incl;     // block total
    }
    __syncthreads();

    // ---- phase 3: scatter to LDS stage, then coalesced uint4 dump ----
    uint2* rbase = records + (size_t)blockIdx.x * capb;
    uint32_t T = sT;
    if (T <= (uint32_t)STCAP) {
        #pragma unroll
        for (int q = 0; q < 4; ++q) {
            uint2 rec = lrec[q];
            uint32_t xq, yq, zq;
            unpack_rec(rec, xq, yq, zq);
            int rx0, rx1, ry0, ry1, rz0, rz1;
            region_range(xq, yq, zq, rx0, rx1, ry0, ry1, rz0, rz1);
            for (int aa = rx0; aa <= rx1; ++aa)
                for (int bb = ry0; bb <= ry1; ++bb)
                    for (int cc = rz0; cc <= rz1; ++cc) {
                        uint32_t slot = atomicAdd(&px[(aa << 5) + (bb << 2) + cc], 1u);
                        stg[slot] = rec;
                    }
        }
        __syncthreads();
        const uint4* s4 = (const uint4*)stg;
        uint4* r4 = (uint4*)rbase;                 // capb*8 is 16B aligned
        uint32_t half = T >> 1;
        for (uint32_t i = threadIdx.x; i < half; i += BLKT)
            r4[i] = s4[i];
        if ((T & 1u) && threadIdx.x == 0)
            rbase[T - 1] = stg[T - 1];
    } else {
        // overflow fallback (cannot trigger for near-uniform data): direct scatter
        #pragma unroll
        for (int q = 0; q < 4; ++q) {
            uint2 rec = lrec[q];
            uint32_t xq, yq, zq;
            unpack_rec(rec, xq, yq, zq);
            int rx0, rx1, ry0, ry1, rz0, rz1;
            region_range(xq, yq, zq, rx0, rx1, ry0, ry1, rz0, rz1);
            for (int aa = rx0; aa <= rx1; ++aa)
                for (int bb = ry0; bb <= ry1; ++bb)
                    for (int cc = rz0; cc <= rz1; ++cc) {
                        uint32_t slot = atomicAdd(&px[(aa << 5) + (bb << 2) + cc], 1u);
                        rbase[slot] = rec;
                    }
        }
    }
}

// ======== pass B: per-region LDS accumulate over per-block segments ========
__device__ __forceinline__ uint2 seg_load(
    const uint32_t* sOff, const uint32_t* sStart, int cnt, int first, int capb,
    const uint2* __restrict__ records, uint32_t r)
{
    int lo = 0, hi = cnt - 1;
    while (lo < hi) {
        int mid = (lo + hi + 1) >> 1;
        if (sOff[mid] <= r) lo = mid; else hi = mid - 1;
    }
    return records[(size_t)(first + lo) * capb + sStart[lo] + (r - sOff[lo])];
}

__device__ __forceinline__ void accum_rec(
    float* tile, uint2 rc, int rx, int ry, int rz)
{
    const float FQ = 6.103515625e-05f;             // 2^-14
    uint32_t xq, yq, zq;
    unpack_rec(rc, xq, yq, zq);
    int ix = xq >> 14, iy = yq >> 14, iz = zq >> 14;
    float fx = (float)(xq & 16383u) * FQ;
    float fy = (float)(yq & 16383u) * FQ;
    float fz = (float)(zq & 16383u) * FQ;
    float wx[2] = {1.0f - fx, fx};
    float wy[2] = {1.0f - fy, fy};
    float wz[2] = {1.0f - fz, fz};
    #pragma unroll
    for (int dx = 0; dx < 2; ++dx) {
        int cx = ix + dx;
        if ((cx >> 4) != rx) continue;
        #pragma unroll
        for (int dy = 0; dy < 2; ++dy) {
            int cy = iy + dy;
            if ((cy >> 4) != ry) continue;
            float wxy = wx[dx] * wy[dy];
            #pragma unroll
            for (int dz = 0; dz < 2; ++dz) {
                int cz = iz + dz;
                if ((cz >> 5) != rz) continue;
                atomicAdd(&tile[(((cx & 15) << 4) + (cy & 15)) * 32 + (cz & 31)],
                          wxy * wz[dz]);
            }
        }
    }
}

__global__ __launch_bounds__(ABLK) void accum_seg(
    const uint32_t* __restrict__ hist, const uint32_t* __restrict__ pfxg,
    const uint2* __restrict__ records, float* __restrict__ out,
    int B, int nb1, int bpg1, int bpg2, int capb)
{
    __shared__ float tile[16 * 16 * 32];           // 32 KB
    __shared__ uint32_t sOff[MAXSEG + 1];          // cumulative counts
    __shared__ uint32_t sStart[MAXSEG];            // per-segment start offset
    int bin = blockIdx.x;
    int cb = bin >> 8;
    int l  = bin & 255;
    int rx = l >> 5, ry = (l >> 2) & 7, rz = l & 3;

    int first = (cb < B) ? cb * bpg1 : nb1 + (cb - B) * bpg2;
    int cnt   = (cb < B) ? bpg1 : bpg2;

    float4* t4 = (float4*)tile;
    for (int t = threadIdx.x; t < 2048; t += ABLK)
        t4[t] = make_float4(0.f, 0.f, 0.f, 0.f);
    if (threadIdx.x < (uint32_t)cnt) {
        sStart[threadIdx.x] = pfxg[(size_t)(first + threadIdx.x) * BPG + l];
        sOff[threadIdx.x]   = hist[(size_t)(first + threadIdx.x) * BPG + l];
    }
    __syncthreads();
    if (threadIdx.x == 0) {
        uint32_t run = 0;
        for (int k = 0; k < cnt; ++k) { uint32_t c = sOff[k]; sOff[k] = run; run += c; }
        sOff[cnt] = run;
    }
    __syncthreads();

    uint32_t total = sOff[cnt];
    // 2x unrolled: issue both loads (independent searches) before the atomics
    uint32_t r = threadIdx.x;
    for (; r + ABLK < total; r += 2 * ABLK) {
        uint2 rc0 = seg_load(sOff, sStart, cnt, first, capb, records, r);
        uint2 rc1 = seg_load(sOff, sStart, cnt, first, capb, records, r + ABLK);
        accum_rec(tile, rc0, rx, ry, rz);
        accum_rec(tile, rc1, rx, ry, rz);
    }
    if (r < total) {
        uint2 rc0 = seg_load(sOff, sStart, cnt, first, capb, records, r);
        accum_rec(tile, rc0, rx, ry, rz);
    }
    __syncthreads();

    // full region store: each (X,Y) z-row is 32 floats = one 128 B line
    float* gout = out + (size_t)cb * R3c;
    for (int w = threadIdx.x; w < 2048; w += ABLK) {
        int lin = w * 4;
        int lx = lin >> 9, rem = lin & 511, ly = rem >> 5, lz = rem & 31;
        int X = rx * 16 + lx, Y = ry * 16 + ly, Z = rz * 32 + lz;
        f4v v = ((const f4v*)tile)[w];
        __builtin_nontemporal_store(v, (f4v*)&gout[((size_t)X * R + Y) * R + Z]);
    }
}

// ---------------- fallback (R1 path) ----------------
__device__ __forceinline__ void point_math_f(float px, float py, float pz,
                                             int& ix, int& iy, int& iz,
                                             float& fx, float& fy, float& fz)
{
    const float inv = 1.0f / 128.0f;
    float vx = (px * inv + 0.5f) * 128.0f;
    float vy = (py * inv + 0.5f) * 128.0f;
    float vz = (pz * inv + 0.5f) * 128.0f;
    float lx = floorf(vx), ly = floorf(vy), lz = floorf(vz);
    fx = vx - lx; fy = vy - ly; fz = vz - lz;
    ix = min(max((int)lx, 0), R - 2);
    iy = min(max((int)ly, 0), R - 2);
    iz = min(max((int)lz, 0), R - 2);
}

__global__ __launch_bounds__(256) void gridding_scatter(
    const float* __restrict__ cloud, float* __restrict__ grid,
    int total_pts, int n_per_batch)
{
    int idx = blockIdx.x * blockDim.x + threadIdx.x;
    if (idx >= total_pts) return;
    int b = idx / n_per_batch;
    const float* p = cloud + (size_t)idx * 3;
    int ix, iy, iz; float fx, fy, fz;
    point_math_f(p[0], p[1], p[2], ix, iy, iz, fx, fy, fz);
    float wx[2] = {1.0f - fx, fx};
    float wy[2] = {1.0f - fy, fy};
    float wz[2] = {1.0f - fz, fz};
    float* gb = grid + (size_t)b * R3c;
    #pragma unroll
    for (int dx = 0; dx < 2; ++dx)
        #pragma unroll
        for (int dy = 0; dy < 2; ++dy) {
            float wxy = wx[dx] * wy[dy];
            #pragma unroll
            for (int dz = 0; dz < 2; ++dz)
                atomicAdd(gb + ((size_t)(ix + dx) * R + (iy + dy)) * R + (iz + dz),
                          wxy * wz[dz]);
        }
}

extern "C" void kernel_launch(void* const* d_in, const int* in_sizes, int n_in,
                              void* d_out, int out_size, void* d_ws, size_t ws_size,
                              hipStream_t stream) {
    const float* pred = (const float*)d_in[0];
    const float* gt   = (const float*)d_in[1];
    float* out = (float*)d_out;

    int total1 = in_sizes[0] / 3;
    int total2 = in_sizes[1] / 3;
    int B  = out_size / (2 * R3c);   // 16
    int n1 = (B > 0) ? total1 / B : 0;
    int n2 = (B > 0) ? total2 / B : 0;
    int P  = total1 + total2;
    int ppb = PPT * BLKT;            // 2048 (fixed per-block point count)

    int capb = 8 * ppb;              // worst-case records per block (16384)
    size_t ws_need = WS_REC + (size_t)NBLK * capb * 8;   // ~130 MB

    // strict fast path: all blocks full, each inside one (cloud,batch)
    bool fastok = (B > 0) && (B <= MAXB) && (n1 > 0) && (n2 > 0) &&
                  (total1 == B * n1) && (total2 == B * n2) &&
                  (P == NBLK * ppb) &&
                  (n1 % ppb == 0) && (n2 % ppb == 0) &&
                  (n1 / ppb <= MAXSEG) && (n2 / ppb <= MAXSEG) &&
                  (ws_size >= ws_need);
    if (!fastok) {
        hipMemsetAsync(d_out, 0, (size_t)out_size * sizeof(float), stream);
        gridding_scatter<<<(total1 + 255) / 256, 256, 0, stream>>>(pred, out, total1, n1);
        gridding_scatter<<<(total2 + 255) / 256, 256, 0, stream>>>(
            gt, out + (size_t)B * R3c, total2, n2);
        return;
    }

    uint32_t* hist = (uint32_t*)((char*)d_ws + WS_HIST);
    uint32_t* pfxg = (uint32_t*)((char*)d_ws + WS_PFX);
    uint2*    recs = (uint2*)((char*)d_ws + WS_REC);

    int nb1  = total1 / ppb;         // blocks for pred (512)
    int bpg1 = n1 / ppb;             // blocks per (pred,batch) (32)
    int bpg2 = n2 / ppb;             // blocks per (gt,batch)   (32)
    int NBINS = 2 * B * BPG;         // 8192

    sort_local<<<NBLK, BLKT, 0, stream>>>(pred, gt, total1, capb, hist, pfxg, recs);
    accum_seg<<<NBINS, ABLK, 0, stream>>>(hist, pfxg, recs, out,
                                          B, nb1, bpg1, bpg2, capb);
}